// Round 13
// baseline (27.074 us; speedup 1.0000x reference)
//
#include <hip/hip_runtime.h>
#include <math.h>

// ConvCaps EM-routing, MI355X — 2-group-per-thread ILP-interleaved EM.
//
// Algebra: vv[n,ci,co,k] = Sv(n,ci,co>>1) * Wsum(sp=n%36,ci,co,k&3), so EM
// runs on a 32x32x4 table. Block = 128 threads handles groups 2b and 2b+1
// phase-interleaved (every serial chain duplicated & independent -> ILP).
// Wave wv owns o = wv*16+(lane&15); cq = lane>>4 owns c = cq*8..cq*8+7.

#define EPSF 1e-8f

typedef float f2 __attribute__((ext_vector_type(2)));

__device__ __forceinline__ float rcpf(float x) { return __builtin_amdgcn_rcpf(x); }

// ---- pre: box-filtered channel sums (S,A) + Wsum[36][32][32][4] (R7) ----
__global__ __launch_bounds__(256) void pre_kernel(
        const float* __restrict__ x, const float* __restrict__ a,
        const float* __restrict__ w,
        float* __restrict__ S, float* __restrict__ A, float* __restrict__ Wsum) {
    int bid = blockIdx.x;
    if (bid < 1088) {
        __shared__ float plane[6272];
        __shared__ float bsum[196];
        const int t = threadIdx.x;
        const float* src = (bid < 1024) ? (x + (size_t)bid * 6272)
                                        : (a + (size_t)(bid - 1024) * 6272);
        for (int k = t; k < 1568; k += 256)
            *(float4*)&plane[k * 4] = *(const float4*)(src + k * 4);
        __syncthreads();
        if (t < 196) {
            float s = 0.f;
#pragma unroll
            for (int c = 0; c < 32; ++c) s += plane[c * 196 + t];
            bsum[t] = s;
        }
        __syncthreads();
        if (t < 36) {
            int oy = t / 6, ox = t - oy * 6;
            const float* q = &bsum[oy * 28 + ox * 2];
            float s = (q[0] + q[1] + q[2]) + (q[14] + q[15] + q[16])
                    + (q[28] + q[29] + q[30]);
            s *= (1.0f / 9.0f);
            if (bid < 1024) S[bid * 36 + t] = s;
            else            A[(bid - 1024) * 36 + t] = s;
        }
    } else {
        int wi = (bid - 1088) * 256 + threadIdx.x;   // 147456 Wsum entries
        int sp = wi >> 12;
        int rr = wi & 4095;
        int ci = rr >> 7, co = (rr >> 2) & 31, j = rr & 3;
        int B = sp * 32 + ci;
        int cc = B / 36;
        int rem = B - cc * 36;
        int wbase = cc * 18432 + (rem / 6) * 3072 + (rem % 6) * 512 + co * 16 + j;
        Wsum[wi] = w[wbase] + w[wbase + 4] + w[wbase + 8] + w[wbase + 12];
    }
}

// ---- EM: one 128-thread block per PAIR of routing groups ----
__global__ __launch_bounds__(128, 2) void em_kernel(
        const float* __restrict__ bu, const float* __restrict__ ba,
        const float* __restrict__ S, const float* __restrict__ A,
        const float* __restrict__ Wsum, float* __restrict__ out) {
    __shared__ float Sv[2][512];
    __shared__ float avs[2][32];
    __shared__ float lgb[2][33 * 32];   // [g][c][o], stride 33

    const int t = threadIdx.x;
    const int w = t >> 6;
    const int lane = t & 63;
    const int o = w * 16 + (lane & 15);
    const int cq = lane >> 4;
    const int c0 = cq * 8;
    const int n0 = blockIdx.x * 2;
    const int bq0 = n0 / 36, sp0 = n0 - bq0 * 36;
    const int n1 = n0 + 1;
    const int bq1 = n1 / 36, sp1 = n1 - bq1 * 36;

    if (t < 64) {
        int g = t >> 5, i = t & 31;
        int bq = g ? bq1 : bq0, sp = g ? sp1 : sp0;
        avs[g][i] = A[bq * 36 + (32 * sp + i) % 36];
    }
    for (int e = t; e < 1024; e += 128) {
        int g = e >> 9, e2 = e & 511;
        int bq = g ? bq1 : bq0, sp = g ? sp1 : sp0;
        int ci = e2 >> 4, hc2 = e2 & 15;
        int B = sp * 32 + ci;
        int cc = B / 36;
        int rem = B - cc * 36;
        int off = cc * 576 + (rem / 6) * 96 + (rem % 6) * 16 + hc2;
        int hi = off / 1152;
        int lo = off - hi * 1152;
        Sv[g][e2] = S[(bq * 16 + hi) * 36 + lo % 36];
    }
    __syncthreads();

    const int hc = o >> 1;
    f2 V2[2][8][2];
    float avr[2][8], r[2][8];
#pragma unroll
    for (int g = 0; g < 2; ++g) {
        const float* Wn = Wsum + (g ? sp1 : sp0) * 4096;
#pragma unroll
        for (int cl = 0; cl < 8; ++cl) {
            int c = c0 + cl;
            float sv = Sv[g][c * 16 + hc];
            float4 w4 = *(const float4*)(Wn + c * 128 + o * 4);
            V2[g][cl][0] = (f2){sv * w4.x, sv * w4.y};
            V2[g][cl][1] = (f2){sv * w4.z, sv * w4.w};
            avr[g][cl] = avs[g][c];
            r[g][cl] = 0.03125f;
        }
    }
    const float bu16 = 16.0f * bu[o];
    const float ba_o = ba[o];
    f2 mu2[2][2], q2[2][2];
    float aout[2] = {0.f, 0.f};
    const float lambdas[3] = {5.0e-4f, 9.75e-4f, 1.42625e-3f};

    for (int it = 0; it < 3; ++it) {
        // ---- pass 1: rp, rs (both groups interleaved) ----
        float rp[2][8], rs[2], rinv[2];
#pragma unroll
        for (int g = 0; g < 2; ++g) {
#pragma unroll
            for (int cl = 0; cl < 8; ++cl) rp[g][cl] = r[g][cl] * avr[g][cl] + EPSF;
            rs[g] = ((rp[g][0] + rp[g][1]) + (rp[g][2] + rp[g][3]))
                  + ((rp[g][4] + rp[g][5]) + (rp[g][6] + rp[g][7]));
        }
        rs[0] += __shfl_xor(rs[0], 16); rs[1] += __shfl_xor(rs[1], 16);
        rs[0] += __shfl_xor(rs[0], 32); rs[1] += __shfl_xor(rs[1], 32);
        rinv[0] = rcpf(rs[0]); rinv[1] = rcpf(rs[1]);
        // ---- mu: 8 independent shuffle chains ----
        {
            f2 m[2][2];
#pragma unroll
            for (int g = 0; g < 2; ++g)
#pragma unroll
            for (int p = 0; p < 2; ++p) {
                f2 a0 = {0.f, 0.f}, a1 = {0.f, 0.f};
#pragma unroll
                for (int cl = 0; cl < 8; cl += 2) {
                    a0 += rp[g][cl] * V2[g][cl][p];
                    a1 += rp[g][cl + 1] * V2[g][cl + 1][p];
                }
                m[g][p] = a0 + a1;
            }
#pragma unroll
            for (int g = 0; g < 2; ++g)
#pragma unroll
            for (int p = 0; p < 2; ++p) {
                m[g][p].x += __shfl_xor(m[g][p].x, 16);
                m[g][p].y += __shfl_xor(m[g][p].y, 16);
            }
#pragma unroll
            for (int g = 0; g < 2; ++g)
#pragma unroll
            for (int p = 0; p < 2; ++p) {
                m[g][p].x += __shfl_xor(m[g][p].x, 32);
                m[g][p].y += __shfl_xor(m[g][p].y, 32);
                mu2[g][p] = m[g][p] * rinv[g];
            }
        }
        // ---- sig: two-pass, fused single log per group ----
        float L[2];
        {
            f2 sg[2][2];
#pragma unroll
            for (int g = 0; g < 2; ++g)
#pragma unroll
            for (int p = 0; p < 2; ++p) {
                f2 a0 = {0.f, 0.f}, a1 = {0.f, 0.f};
#pragma unroll
                for (int cl = 0; cl < 8; cl += 2) {
                    f2 d0 = V2[g][cl][p] - mu2[g][p];
                    f2 d1 = V2[g][cl + 1][p] - mu2[g][p];
                    a0 += (d0 * d0) * rp[g][cl];
                    a1 += (d1 * d1) * rp[g][cl + 1];
                }
                sg[g][p] = a0 + a1;
            }
#pragma unroll
            for (int g = 0; g < 2; ++g)
#pragma unroll
            for (int p = 0; p < 2; ++p) {
                sg[g][p].x += __shfl_xor(sg[g][p].x, 16);
                sg[g][p].y += __shfl_xor(sg[g][p].y, 16);
            }
#pragma unroll
            for (int g = 0; g < 2; ++g)
#pragma unroll
            for (int p = 0; p < 2; ++p) {
                sg[g][p].x += __shfl_xor(sg[g][p].x, 32);
                sg[g][p].y += __shfl_xor(sg[g][p].y, 32);
                sg[g][p] = sg[g][p] * rinv[g] + EPSF;
                q2[g][p] = (f2){2.0f * rcpf(sg[g][p].x), 2.0f * rcpf(sg[g][p].y)};
            }
#pragma unroll
            for (int g = 0; g < 2; ++g)
                L[g] = __logf((sg[g][0].x * sg[g][0].y) * (sg[g][1].x * sg[g][1].y));
        }
#pragma unroll
        for (int g = 0; g < 2; ++g) {
            float cost = (bu16 + 2.0f * L[g]) * rs[g];
            float z = lambdas[it] * (ba_o - cost);
            aout[g] = rcpf(1.0f + __expf(-z));
        }

        if (it < 2) {
#pragma unroll
            for (int g = 0; g < 2; ++g) {
                float T = __logf(aout[g]) - 2.0f * L[g];
#pragma unroll
                for (int cl = 0; cl < 8; ++cl) {
                    f2 d0 = V2[g][cl][0] - mu2[g][0];
                    f2 d1 = V2[g][cl][1] - mu2[g][1];
                    f2 s2 = (d0 * d0) * q2[g][0] + (d1 * d1) * q2[g][1];
                    lgb[g][(c0 + cl) * 33 + o] = T - (s2.x + s2.y);
                }
            }
            __syncthreads();
            // transposed softmax: thread -> (c-row, o-quarter), both groups
            {
                int cT = t >> 2, q = t & 3;
#pragma unroll
                for (int g = 0; g < 2; ++g) {
                    float* rowp = &lgb[g][cT * 33 + q * 8];
                    float4 u0 = *(float4*)(rowp);
                    float4 u1 = *(float4*)(rowp + 4);
                    float m0 = fmaxf(fmaxf(u0.x, u0.y), fmaxf(u0.z, u0.w));
                    float m1 = fmaxf(fmaxf(u1.x, u1.y), fmaxf(u1.z, u1.w));
                    float m = fmaxf(m0, m1);
                    m = fmaxf(m, __shfl_xor(m, 1));
                    m = fmaxf(m, __shfl_xor(m, 2));
                    u0.x = __expf(u0.x - m); u0.y = __expf(u0.y - m);
                    u0.z = __expf(u0.z - m); u0.w = __expf(u0.w - m);
                    u1.x = __expf(u1.x - m); u1.y = __expf(u1.y - m);
                    u1.z = __expf(u1.z - m); u1.w = __expf(u1.w - m);
                    float s0 = (u0.x + u0.y) + (u0.z + u0.w);
                    float s1 = (u1.x + u1.y) + (u1.z + u1.w);
                    float ssum = s0 + s1;
                    ssum += __shfl_xor(ssum, 1);
                    ssum += __shfl_xor(ssum, 2);
                    float inv = rcpf(ssum);
                    u0.x *= inv; u0.y *= inv; u0.z *= inv; u0.w *= inv;
                    u1.x *= inv; u1.y *= inv; u1.z *= inv; u1.w *= inv;
                    *(float4*)(rowp)     = u0;
                    *(float4*)(rowp + 4) = u1;
                }
            }
            __syncthreads();
#pragma unroll
            for (int g = 0; g < 2; ++g)
#pragma unroll
            for (int cl = 0; cl < 8; ++cl)
                r[g][cl] = lgb[g][(c0 + cl) * 33 + o];
        }
    }

    // outputs: mu expanded to 16 k; 4 cq-lanes each write one float4 quarter
#pragma unroll
    for (int g = 0; g < 2; ++g) {
        int n = n0 + g;
        float4 val = {mu2[g][0].x, mu2[g][0].y, mu2[g][1].x, mu2[g][1].y};
        float4* po = (float4*)(out + n * 512 + o * 16);
        po[cq] = val;
        if (cq == 0) out[1179648 + n * 32 + o] = aout[g];
    }
}

extern "C" void kernel_launch(void* const* d_in, const int* in_sizes, int n_in,
                              void* d_out, int out_size, void* d_ws, size_t ws_size,
                              hipStream_t stream) {
    const float* x = (const float*)d_in[0];
    const float* a = (const float*)d_in[1];
    const float* w = (const float*)d_in[2];
    const float* bu = (const float*)d_in[3];
    const float* ba = (const float*)d_in[4];
    float* out = (float*)d_out;

    float* S    = (float*)d_ws;          // 36864
    float* A    = S + 36864;             // 2304
    float* Wsum = A + 2304;              // 147456

    pre_kernel<<<1088 + 576, 256, 0, stream>>>(x, a, w, S, A, Wsum);
    em_kernel<<<1152, 128, 0, stream>>>(bu, ba, S, A, Wsum, out);
}

// Round 15
// 22.829 us; speedup vs baseline: 1.1859x; 1.1859x over previous
//
#include <hip/hip_runtime.h>
#include <math.h>

// ConvCaps EM-routing, MI355X — R12 structure; 4-lane reductions via
// gfx950 permlane16/32_swap BUILTINS (VALU full-rate, no DS pipe).
//
// Algebra: vv[n,ci,co,k] = Sv(n,ci,co>>1) * Wsum(sp=n%36,ci,co,k&3), so EM
// runs on a 32x32x4 table. EM block = 128 threads (2 waves) per group.
// Wave wv owns o = wv*16+(lane&15); cq = lane>>4 owns c = cq*8..cq*8+7.

#define EPSF 1e-8f

typedef float f2 __attribute__((ext_vector_type(2)));
typedef unsigned u32x2 __attribute__((ext_vector_type(2)));

__device__ __forceinline__ float rcpf(float x) { return __builtin_amdgcn_rcpf(x); }

// sum over the 4 lanes {l, l^16, l^32, l^48}; result in all 4 lanes.
// Builtin returns BOTH post-swap registers -> no register-aliasing hazard
// (R14's inline-asm "+v"/"+v" on identical values coalesced to one VGPR).
__device__ __forceinline__ float reduce4(float x) {
#if __has_builtin(__builtin_amdgcn_permlane16_swap) && __has_builtin(__builtin_amdgcn_permlane32_swap)
    unsigned xu = __float_as_uint(x);
    u32x2 p = __builtin_amdgcn_permlane16_swap(xu, xu, false, false);
    float s = __uint_as_float(p.x) + __uint_as_float(p.y);
    unsigned su = __float_as_uint(s);
    u32x2 q = __builtin_amdgcn_permlane32_swap(su, su, false, false);
    return __uint_as_float(q.x) + __uint_as_float(q.y);
#else
    x += __shfl_xor(x, 16);
    x += __shfl_xor(x, 32);
    return x;
#endif
}

// ---- pre: box-filtered channel sums (S,A) + Wsum[36][32][32][4] (R7) ----
__global__ __launch_bounds__(256) void pre_kernel(
        const float* __restrict__ x, const float* __restrict__ a,
        const float* __restrict__ w,
        float* __restrict__ S, float* __restrict__ A, float* __restrict__ Wsum) {
    int bid = blockIdx.x;
    if (bid < 1088) {
        __shared__ float plane[6272];
        __shared__ float bsum[196];
        const int t = threadIdx.x;
        const float* src = (bid < 1024) ? (x + (size_t)bid * 6272)
                                        : (a + (size_t)(bid - 1024) * 6272);
        for (int k = t; k < 1568; k += 256)
            *(float4*)&plane[k * 4] = *(const float4*)(src + k * 4);
        __syncthreads();
        if (t < 196) {
            float s = 0.f;
#pragma unroll
            for (int c = 0; c < 32; ++c) s += plane[c * 196 + t];
            bsum[t] = s;
        }
        __syncthreads();
        if (t < 36) {
            int oy = t / 6, ox = t - oy * 6;
            const float* q = &bsum[oy * 28 + ox * 2];
            float s = (q[0] + q[1] + q[2]) + (q[14] + q[15] + q[16])
                    + (q[28] + q[29] + q[30]);
            s *= (1.0f / 9.0f);
            if (bid < 1024) S[bid * 36 + t] = s;
            else            A[(bid - 1024) * 36 + t] = s;
        }
    } else {
        int wi = (bid - 1088) * 256 + threadIdx.x;   // 147456 Wsum entries
        int sp = wi >> 12;
        int rr = wi & 4095;
        int ci = rr >> 7, co = (rr >> 2) & 31, j = rr & 3;
        int B = sp * 32 + ci;
        int cc = B / 36;
        int rem = B - cc * 36;
        int wbase = cc * 18432 + (rem / 6) * 3072 + (rem % 6) * 512 + co * 16 + j;
        Wsum[wi] = w[wbase] + w[wbase + 4] + w[wbase + 8] + w[wbase + 12];
    }
}

// ---- EM: one 128-thread block (2 waves) per routing group ----
__global__ __launch_bounds__(128, 4) void em_kernel(
        const float* __restrict__ bu, const float* __restrict__ ba,
        const float* __restrict__ S, const float* __restrict__ A,
        const float* __restrict__ Wsum, float* __restrict__ out) {
    __shared__ float Sv[512];
    __shared__ float avs[32];
    __shared__ float lgb[33 * 32];      // [c][o], stride 33

    const int t = threadIdx.x;
    const int w = t >> 6;
    const int lane = t & 63;
    const int o = w * 16 + (lane & 15); // owned output capsule
    const int cq = lane >> 4;           // c-quarter (0..3)
    const int c0 = cq * 8;
    const int n = blockIdx.x;
    const int bq = n / 36;
    const int sp = n - bq * 36;

    if (t < 32) avs[t] = A[bq * 36 + (32 * sp + t) % 36];
    for (int e = t; e < 512; e += 128) {
        int ci = e >> 4, hc2 = e & 15;
        int B = sp * 32 + ci;
        int cc = B / 36;
        int rem = B - cc * 36;
        int off = cc * 576 + (rem / 6) * 96 + (rem % 6) * 16 + hc2;
        int hi = off / 1152;
        int lo = off - hi * 1152;
        Sv[e] = S[(bq * 16 + hi) * 36 + lo % 36];
    }
    __syncthreads();

    const int hc = o >> 1;
    f2 V2[8][2];
    float avr[8], r[8];
    const float* Wn = Wsum + sp * 4096;
#pragma unroll
    for (int cl = 0; cl < 8; ++cl) {
        int c = c0 + cl;
        float sv = Sv[c * 16 + hc];
        float4 w4 = *(const float4*)(Wn + c * 128 + o * 4);
        V2[cl][0] = (f2){sv * w4.x, sv * w4.y};
        V2[cl][1] = (f2){sv * w4.z, sv * w4.w};
        avr[cl] = avs[c];
        r[cl] = 0.03125f;
    }
    const float bu16 = 16.0f * bu[o];
    const float ba_o = ba[o];
    f2 mu2[2], q2[2];
    float aout = 0.f;
    const float lambdas[3] = {5.0e-4f, 9.75e-4f, 1.42625e-3f};

    for (int it = 0; it < 3; ++it) {
        // ---- pass 1: rp, rs, mu (4-lane reduce via permlane swaps) ----
        float rp[8];
#pragma unroll
        for (int cl = 0; cl < 8; ++cl) rp[cl] = r[cl] * avr[cl] + EPSF;
        float rs = ((rp[0] + rp[1]) + (rp[2] + rp[3]))
                 + ((rp[4] + rp[5]) + (rp[6] + rp[7]));
        rs = reduce4(rs);
        float rinv = rcpf(rs);
#pragma unroll
        for (int p = 0; p < 2; ++p) {
            f2 a0 = {0.f, 0.f}, a1 = {0.f, 0.f};
#pragma unroll
            for (int cl = 0; cl < 8; cl += 2) {
                a0 += rp[cl] * V2[cl][p];
                a1 += rp[cl + 1] * V2[cl + 1][p];
            }
            f2 m = a0 + a1;
            m.x = reduce4(m.x);
            m.y = reduce4(m.y);
            mu2[p] = m * rinv;
        }
        // ---- pass 2: sig (non-negative), single fused log ----
        float L;
        {
            f2 sgv[2];
#pragma unroll
            for (int p = 0; p < 2; ++p) {
                f2 a0 = {0.f, 0.f}, a1 = {0.f, 0.f};
#pragma unroll
                for (int cl = 0; cl < 8; cl += 2) {
                    f2 d0 = V2[cl][p] - mu2[p];
                    f2 d1 = V2[cl + 1][p] - mu2[p];
                    a0 += (d0 * d0) * rp[cl];
                    a1 += (d1 * d1) * rp[cl + 1];
                }
                f2 sg = a0 + a1;
                sg.x = reduce4(sg.x);
                sg.y = reduce4(sg.y);
                sgv[p] = sg * rinv + EPSF;
                q2[p] = (f2){2.0f * rcpf(sgv[p].x), 2.0f * rcpf(sgv[p].y)};
            }
            L = __logf((sgv[0].x * sgv[0].y) * (sgv[1].x * sgv[1].y));
        }
        float cost = (bu16 + 2.0f * L) * rs;
        float z = lambdas[it] * (ba_o - cost);
        aout = rcpf(1.0f + __expf(-z));

        if (it < 2) {
            // logits (softmax-invariant -8*log2pi dropped)
            float T = __logf(aout) - 2.0f * L;
#pragma unroll
            for (int cl = 0; cl < 8; ++cl) {
                f2 d0 = V2[cl][0] - mu2[0];
                f2 d1 = V2[cl][1] - mu2[1];
                f2 s2 = (d0 * d0) * q2[0] + (d1 * d1) * q2[1];
                lgb[(c0 + cl) * 33 + o] = T - (s2.x + s2.y);
            }
            __syncthreads();
            // transposed softmax: 128 lanes, lane = (c-row, quarter of o-row)
            // (R12's shfl_xor kept — one experimental variable per round)
            {
                int cT = t >> 2, q = t & 3;
                float* rowp = &lgb[cT * 33 + q * 8];
                float4 u0 = *(float4*)(rowp);
                float4 u1 = *(float4*)(rowp + 4);
                float m0 = fmaxf(fmaxf(u0.x, u0.y), fmaxf(u0.z, u0.w));
                float m1 = fmaxf(fmaxf(u1.x, u1.y), fmaxf(u1.z, u1.w));
                float m = fmaxf(m0, m1);
                m = fmaxf(m, __shfl_xor(m, 1));
                m = fmaxf(m, __shfl_xor(m, 2));
                u0.x = __expf(u0.x - m); u0.y = __expf(u0.y - m);
                u0.z = __expf(u0.z - m); u0.w = __expf(u0.w - m);
                u1.x = __expf(u1.x - m); u1.y = __expf(u1.y - m);
                u1.z = __expf(u1.z - m); u1.w = __expf(u1.w - m);
                float s0 = (u0.x + u0.y) + (u0.z + u0.w);
                float s1 = (u1.x + u1.y) + (u1.z + u1.w);
                float ssum = s0 + s1;
                ssum += __shfl_xor(ssum, 1);
                ssum += __shfl_xor(ssum, 2);
                float inv = rcpf(ssum);
                u0.x *= inv; u0.y *= inv; u0.z *= inv; u0.w *= inv;
                u1.x *= inv; u1.y *= inv; u1.z *= inv; u1.w *= inv;
                *(float4*)(rowp)     = u0;
                *(float4*)(rowp + 4) = u1;
            }
            __syncthreads();
#pragma unroll
            for (int cl = 0; cl < 8; ++cl)
                r[cl] = lgb[(c0 + cl) * 33 + o];
        }
    }

    // outputs: mu expanded to 16 k (k>>2 drops out); 4 cq-lanes hold identical
    // mu for their o — each writes one float4 quarter of the 16-k row.
    float4 val = {mu2[0].x, mu2[0].y, mu2[1].x, mu2[1].y};
    float4* po = (float4*)(out + n * 512 + o * 16);
    po[cq] = val;
    if (cq == 0) out[1179648 + n * 32 + o] = aout;
}

extern "C" void kernel_launch(void* const* d_in, const int* in_sizes, int n_in,
                              void* d_out, int out_size, void* d_ws, size_t ws_size,
                              hipStream_t stream) {
    const float* x = (const float*)d_in[0];
    const float* a = (const float*)d_in[1];
    const float* w = (const float*)d_in[2];
    const float* bu = (const float*)d_in[3];
    const float* ba = (const float*)d_in[4];
    float* out = (float*)d_out;

    float* S    = (float*)d_ws;          // 36864
    float* A    = S + 36864;             // 2304
    float* Wsum = A + 2304;              // 147456

    pre_kernel<<<1088 + 576, 256, 0, stream>>>(x, a, w, S, A, Wsum);
    em_kernel<<<2304, 128, 0, stream>>>(bu, ba, S, A, Wsum, out);
}

// Round 16
// 22.136 us; speedup vs baseline: 1.2230x; 1.0313x over previous
//
#include <hip/hip_runtime.h>
#include <math.h>

// ConvCaps EM-routing, MI355X — R15 + direct-gather setup (no Sv staging /
// no initial barrier), DPP quad_perm softmax swaps, log-sigmoid identity.
//
// Algebra: vv[n,ci,co,k] = Sv(n,ci,co>>1) * Wsum(sp=n%36,ci,co,k&3), so EM
// runs on a 32x32x4 table. EM block = 128 threads (2 waves) per group.
// Wave wv owns o = wv*16+(lane&15); cq = lane>>4 owns c = cq*8..cq*8+7.

#define EPSF 1e-8f

typedef float f2 __attribute__((ext_vector_type(2)));
typedef unsigned u32x2 __attribute__((ext_vector_type(2)));

__device__ __forceinline__ float rcpf(float x) { return __builtin_amdgcn_rcpf(x); }

// sum over the 4 lanes {l, l^16, l^32, l^48}; result in all 4 lanes.
__device__ __forceinline__ float reduce4(float x) {
#if __has_builtin(__builtin_amdgcn_permlane16_swap) && __has_builtin(__builtin_amdgcn_permlane32_swap)
    unsigned xu = __float_as_uint(x);
    u32x2 p = __builtin_amdgcn_permlane16_swap(xu, xu, false, false);
    float s = __uint_as_float(p.x) + __uint_as_float(p.y);
    unsigned su = __float_as_uint(s);
    u32x2 q = __builtin_amdgcn_permlane32_swap(su, su, false, false);
    return __uint_as_float(q.x) + __uint_as_float(q.y);
#else
    x += __shfl_xor(x, 16);
    x += __shfl_xor(x, 32);
    return x;
#endif
}

// intra-quad lane swaps via DPP (full-rate VALU, no DS pipe)
__device__ __forceinline__ float dpp_xor1(float x) {
    return __int_as_float(__builtin_amdgcn_update_dpp(
        0, __float_as_int(x), 0xB1, 0xF, 0xF, true));   // quad_perm [1,0,3,2]
}
__device__ __forceinline__ float dpp_xor2(float x) {
    return __int_as_float(__builtin_amdgcn_update_dpp(
        0, __float_as_int(x), 0x4E, 0xF, 0xF, true));   // quad_perm [2,3,0,1]
}

// ---- pre: box-filtered channel sums (S,A) + Wsum[36][32][32][4] (R7) ----
__global__ __launch_bounds__(256) void pre_kernel(
        const float* __restrict__ x, const float* __restrict__ a,
        const float* __restrict__ w,
        float* __restrict__ S, float* __restrict__ A, float* __restrict__ Wsum) {
    int bid = blockIdx.x;
    if (bid < 1088) {
        __shared__ float plane[6272];
        __shared__ float bsum[196];
        const int t = threadIdx.x;
        const float* src = (bid < 1024) ? (x + (size_t)bid * 6272)
                                        : (a + (size_t)(bid - 1024) * 6272);
        for (int k = t; k < 1568; k += 256)
            *(float4*)&plane[k * 4] = *(const float4*)(src + k * 4);
        __syncthreads();
        if (t < 196) {
            float s = 0.f;
#pragma unroll
            for (int c = 0; c < 32; ++c) s += plane[c * 196 + t];
            bsum[t] = s;
        }
        __syncthreads();
        if (t < 36) {
            int oy = t / 6, ox = t - oy * 6;
            const float* q = &bsum[oy * 28 + ox * 2];
            float s = (q[0] + q[1] + q[2]) + (q[14] + q[15] + q[16])
                    + (q[28] + q[29] + q[30]);
            s *= (1.0f / 9.0f);
            if (bid < 1024) S[bid * 36 + t] = s;
            else            A[(bid - 1024) * 36 + t] = s;
        }
    } else {
        int wi = (bid - 1088) * 256 + threadIdx.x;   // 147456 Wsum entries
        int sp = wi >> 12;
        int rr = wi & 4095;
        int ci = rr >> 7, co = (rr >> 2) & 31, j = rr & 3;
        int B = sp * 32 + ci;
        int cc = B / 36;
        int rem = B - cc * 36;
        int wbase = cc * 18432 + (rem / 6) * 3072 + (rem % 6) * 512 + co * 16 + j;
        Wsum[wi] = w[wbase] + w[wbase + 4] + w[wbase + 8] + w[wbase + 12];
    }
}

// ---- EM: one 128-thread block (2 waves) per routing group ----
__global__ __launch_bounds__(128, 4) void em_kernel(
        const float* __restrict__ bu, const float* __restrict__ ba,
        const float* __restrict__ S, const float* __restrict__ A,
        const float* __restrict__ Wsum, float* __restrict__ out) {
    __shared__ float lgb[33 * 32];      // [c][o], stride 33 (only LDS use)

    const int t = threadIdx.x;
    const int w = t >> 6;
    const int lane = t & 63;
    const int o = w * 16 + (lane & 15); // owned output capsule
    const int cq = lane >> 4;           // c-quarter (0..3)
    const int c0 = cq * 8;
    const int n = blockIdx.x;
    const int bq = n / 36;
    const int sp = n - bq * 36;

    // ---- setup: 24 independent gathers (S/A are L2-hot), no staging barrier
    const int hc = o >> 1;
    f2 V2[8][2];
    float avr[8], r[8];
    const float* Wn = Wsum + sp * 4096;
#pragma unroll
    for (int cl = 0; cl < 8; ++cl) {
        int c = c0 + cl;
        int B = sp * 32 + c;
        int cc = B / 36;
        int rem = B - cc * 36;
        int off = cc * 576 + (rem / 6) * 96 + (rem % 6) * 16 + hc;
        int hi = off / 1152;
        int lo = off - hi * 1152;
        float sv = S[(bq * 16 + hi) * 36 + lo % 36];
        float4 w4 = *(const float4*)(Wn + c * 128 + o * 4);
        V2[cl][0] = (f2){sv * w4.x, sv * w4.y};
        V2[cl][1] = (f2){sv * w4.z, sv * w4.w};
        avr[cl] = A[bq * 36 + (32 * sp + c) % 36];
        r[cl] = 0.03125f;
    }
    const float bu16 = 16.0f * bu[o];
    const float ba_o = ba[o];
    f2 mu2[2], q2[2];
    float aout = 0.f;
    const float lambdas[3] = {5.0e-4f, 9.75e-4f, 1.42625e-3f};

    for (int it = 0; it < 3; ++it) {
        // ---- pass 1: rp, rs, mu (4-lane reduce via permlane swaps) ----
        float rp[8];
#pragma unroll
        for (int cl = 0; cl < 8; ++cl) rp[cl] = r[cl] * avr[cl] + EPSF;
        float rs = ((rp[0] + rp[1]) + (rp[2] + rp[3]))
                 + ((rp[4] + rp[5]) + (rp[6] + rp[7]));
        rs = reduce4(rs);
        float rinv = rcpf(rs);
#pragma unroll
        for (int p = 0; p < 2; ++p) {
            f2 a0 = {0.f, 0.f}, a1 = {0.f, 0.f};
#pragma unroll
            for (int cl = 0; cl < 8; cl += 2) {
                a0 += rp[cl] * V2[cl][p];
                a1 += rp[cl + 1] * V2[cl + 1][p];
            }
            f2 m = a0 + a1;
            m.x = reduce4(m.x);
            m.y = reduce4(m.y);
            mu2[p] = m * rinv;
        }
        // ---- pass 2: sig (non-negative), single fused log ----
        float L;
        {
            f2 sgv[2];
#pragma unroll
            for (int p = 0; p < 2; ++p) {
                f2 a0 = {0.f, 0.f}, a1 = {0.f, 0.f};
#pragma unroll
                for (int cl = 0; cl < 8; cl += 2) {
                    f2 d0 = V2[cl][p] - mu2[p];
                    f2 d1 = V2[cl + 1][p] - mu2[p];
                    a0 += (d0 * d0) * rp[cl];
                    a1 += (d1 * d1) * rp[cl + 1];
                }
                f2 sg = a0 + a1;
                sg.x = reduce4(sg.x);
                sg.y = reduce4(sg.y);
                sgv[p] = sg * rinv + EPSF;
                q2[p] = (f2){2.0f * rcpf(sgv[p].x), 2.0f * rcpf(sgv[p].y)};
            }
            L = __logf((sgv[0].x * sgv[0].y) * (sgv[1].x * sgv[1].y));
        }
        float cost = (bu16 + 2.0f * L) * rs;
        float z = lambdas[it] * (ba_o - cost);

        if (it < 2) {
            // log-sigmoid identity: log(aout) = -log(1 + e^-z)  (skip the rcp)
            float la = -__logf(1.0f + __expf(-z));
            float T = la - 2.0f * L;
#pragma unroll
            for (int cl = 0; cl < 8; ++cl) {
                f2 d0 = V2[cl][0] - mu2[0];
                f2 d1 = V2[cl][1] - mu2[1];
                f2 s2 = (d0 * d0) * q2[0] + (d1 * d1) * q2[1];
                lgb[(c0 + cl) * 33 + o] = T - (s2.x + s2.y);
            }
            __syncthreads();
            // transposed softmax: 128 lanes, lane = (c-row, quarter of o-row)
            {
                int cT = t >> 2, q = t & 3;
                float* rowp = &lgb[cT * 33 + q * 8];
                float4 u0 = *(float4*)(rowp);
                float4 u1 = *(float4*)(rowp + 4);
                float m0 = fmaxf(fmaxf(u0.x, u0.y), fmaxf(u0.z, u0.w));
                float m1 = fmaxf(fmaxf(u1.x, u1.y), fmaxf(u1.z, u1.w));
                float m = fmaxf(m0, m1);
                m = fmaxf(m, dpp_xor1(m));
                m = fmaxf(m, dpp_xor2(m));
                u0.x = __expf(u0.x - m); u0.y = __expf(u0.y - m);
                u0.z = __expf(u0.z - m); u0.w = __expf(u0.w - m);
                u1.x = __expf(u1.x - m); u1.y = __expf(u1.y - m);
                u1.z = __expf(u1.z - m); u1.w = __expf(u1.w - m);
                float s0 = (u0.x + u0.y) + (u0.z + u0.w);
                float s1 = (u1.x + u1.y) + (u1.z + u1.w);
                float ssum = s0 + s1;
                ssum += dpp_xor1(ssum);
                ssum += dpp_xor2(ssum);
                float inv = rcpf(ssum);
                u0.x *= inv; u0.y *= inv; u0.z *= inv; u0.w *= inv;
                u1.x *= inv; u1.y *= inv; u1.z *= inv; u1.w *= inv;
                *(float4*)(rowp)     = u0;
                *(float4*)(rowp + 4) = u1;
            }
            __syncthreads();
#pragma unroll
            for (int cl = 0; cl < 8; ++cl)
                r[cl] = lgb[(c0 + cl) * 33 + o];
        } else {
            aout = rcpf(1.0f + __expf(-z));
        }
    }

    // outputs: mu expanded to 16 k (k>>2 drops out); 4 cq-lanes hold identical
    // mu for their o — each writes one float4 quarter of the 16-k row.
    float4 val = {mu2[0].x, mu2[0].y, mu2[1].x, mu2[1].y};
    float4* po = (float4*)(out + n * 512 + o * 16);
    po[cq] = val;
    if (cq == 0) out[1179648 + n * 32 + o] = aout;
}

extern "C" void kernel_launch(void* const* d_in, const int* in_sizes, int n_in,
                              void* d_out, int out_size, void* d_ws, size_t ws_size,
                              hipStream_t stream) {
    const float* x = (const float*)d_in[0];
    const float* a = (const float*)d_in[1];
    const float* w = (const float*)d_in[2];
    const float* bu = (const float*)d_in[3];
    const float* ba = (const float*)d_in[4];
    float* out = (float*)d_out;

    float* S    = (float*)d_ws;          // 36864
    float* A    = S + 36864;             // 2304
    float* Wsum = A + 2304;              // 147456

    pre_kernel<<<1088 + 576, 256, 0, stream>>>(x, a, w, S, A, Wsum);
    em_kernel<<<2304, 128, 0, stream>>>(bu, ba, S, A, Wsum, out);
}